// Round 17
// baseline (64.726 us; speedup 1.0000x reference)
//
#include <hip/hip_runtime.h>
#include <hip/hip_bf16.h>
#include <math.h>

// ProbaV cPSNR:  loss(u,v) = E[d^2] - (E[d])^2,  d = ct - pm_window(u,v)
// S1(u,v) = T1 - W1(u,v);  S2(u,v) = T2 - 2*CC(u,v) + W2(u,v)
//   T1,T2   : sum ct, sum ct^2            (ct = target*mask, inner 378x378 @ +3)
//   CC(u,v) : sum ct[r][c] * pm[r+u][c+v] (pm = predict*mask)
//   W1,W2   : window sums of pm, pm^2 over rows [u,u+378) x cols [v,v+378)
// W = Total - BR(u) - BC(v) + X(u,v)  (inclusion-exclusion, rows 0..382 x cols 0..383)
//
// R17: async global->LDS staging. R3-R16 evidence: every register-only variant
// has per-wave life ~ #loads x L2-latency (intra-wave serialization); reg
// prefetch (R11) neutral; spill traffic proves HW sustains 2.4 TB/s given
// independent requests. So: stage raw predict/mask slabs (37 rows x 96f,
// 384B stride) via __builtin_amdgcn_global_load_lds width=16 (~7 independent
// DMA issues/thread), one barrier, compute everything from LDS.
// gload_lds writes linearly (wave base + lane*16) -> swizzle must be
// both-sides-or-neither: pre-swizzled GLOBAL source (granule involution
// j' = (j&~7)|((j&7)^(row&7))) + same XOR on ds_read. Derived: 8 lanes/group
// uniform = conflict-free. Edge blocks 0..63 (R13). Two dispatches (R5).

#define NIMG 32
#define IMGSZ (384 * 384)
#define RB 32                    // ct rows per cc block
#define NRB 12                   // row blocks (last: rows 352..377 + mask)
#define NCB 6                    // col blocks (64 cols each)
#define NCC (NIMG * NRB * NCB)   // 2304
#define NEDGE 64                 // 2 per image, blockIdx 0..63
#define SCH 288                  // 2304 / 8 (bijective XCD swizzle)
#define NM 40                    // cc[36], t1, t2, tot1, tot2
#define MSTRIDE 2304             // mpart col-major [NM][MSTRIDE]
#define MQUADS 576               // MSTRIDE/4
#define NE 262                   // edge entries per image
#define SLABR 37                 // slab rows (RB + 5)
#define GRAN 24                  // 16B granules per slab row (96 floats)
#define NCHUNK 14                // ceil(37*24/64) wave-issues per buffer
#define NGRP (NCHUNK * 64)       // 896 granules (padded; 888 logical)

__global__ __launch_bounds__(256) void probav_fused_kernel(
    const float* __restrict__ predict,
    const float* __restrict__ target,
    const float* __restrict__ mask,
    float* __restrict__ mpart /* [NM][MSTRIDE] */,
    double* __restrict__ epart /* [NE][NIMG] */) {

  __shared__ float Pl[NGRP * 4];   // 14336 B (predict slab, swizzled layout)
  __shared__ float Ml[NGRP * 4];   // 14336 B (mask slab)
  __shared__ float red[4 * NM];

  const int t = threadIdx.x;
  const int lane = t & 63;
  const int w = t >> 6;

  if (blockIdx.x >= NEDGE) {
    // ---------------- cc path: 32 ct rows x 64 ct cols per block ----------------
    const int sb = blockIdx.x - NEDGE;             // 0..2303
    const int cb = (sb & 7) * SCH + (sb >> 3);     // bijective on 2304
    const int img = cb / (NRB * NCB);
    const int rem = cb - img * (NRB * NCB);
    const int rb  = rem / NCB;
    const int jcb = rem - rb * NCB;
    const int r0  = rb * RB;
    const int jb0 = jcb * 64;
    const size_t base = (size_t)img * IMGSZ;

    // ---- issue ct global loads first (latency hides under staging) ----
    const int s   = t & 7;               // col seg 0..7
    const int rIn = t >> 3;              // row in tile 0..31
    const int rr  = r0 + rIn;
    const bool rowValid = (rr < 378);
    const int inRow = rowValid ? (rr + 3) : 380;
    const int jb = jb0 + 8 * s;
    const float4* tq = reinterpret_cast<const float4*>(target + base + (size_t)inRow * 384 + jb);
    const float4* mq = reinterpret_cast<const float4*>(mask   + base + (size_t)inRow * 384 + jb);
    float4 tva = tq[0], tvb = tq[1], tvc = tq[2];
    float4 mva = mq[0], mvb = mq[1], mvc = mq[2];

    // ---- stage P and M slabs: async DMA, pre-swizzled global source ----
    for (int c = w; c < NCHUNK; c += 4) {
      const int k = c * 64 + lane;                 // linear granule 0..895
      int row = k / GRAN;
      const int jl = k - row * GRAN;               // 0..23
      if (row > SLABR - 1) row = SLABR - 1;        // pad granules: junk, never read
      const int j2 = (jl & ~7) | ((jl & 7) ^ (row & 7));   // involution
      int col = jb0 + 4 * j2; if (col > 380) col = 380;    // in-row clamp
      int grow = r0 + row;    if (grow > 383) grow = 383;
      const float* ps = predict + base + (size_t)grow * 384 + col;
      const float* ms = mask    + base + (size_t)grow * 384 + col;
      __builtin_amdgcn_global_load_lds(
          (const __attribute__((address_space(1))) void*)ps,
          (__attribute__((address_space(3))) void*)&Pl[c * 256], 16, 0, 0);
      __builtin_amdgcn_global_load_lds(
          (const __attribute__((address_space(1))) void*)ms,
          (__attribute__((address_space(3))) void*)&Ml[c * 256], 16, 0, 0);
    }

    // ---- ct values from registers ----
    float ct[8];
    float t1 = 0.f, t2 = 0.f;
    {
      float tv[12], mv[12];
      tv[0]=tva.x; tv[1]=tva.y; tv[2]=tva.z; tv[3]=tva.w;
      tv[4]=tvb.x; tv[5]=tvb.y; tv[6]=tvb.z; tv[7]=tvb.w;
      tv[8]=tvc.x; tv[9]=tvc.y; tv[10]=tvc.z; tv[11]=tvc.w;
      mv[0]=mva.x; mv[1]=mva.y; mv[2]=mva.z; mv[3]=mva.w;
      mv[4]=mvb.x; mv[5]=mvb.y; mv[6]=mvb.z; mv[7]=mvb.w;
      mv[8]=mvc.x; mv[9]=mvc.y; mv[10]=mvc.z; mv[11]=mvc.w;
#pragma unroll
      for (int x = 0; x < 8; ++x) {
        float v = tv[3 + x] * mv[3 + x];
        v = (rowValid && (jb + x < 378)) ? v : 0.f;
        ct[x] = v;
        t1 += v;
        t2 = fmaf(v, v, t2);
      }
    }

    __syncthreads();   // drains vmcnt (gload_lds tracked by vmcnt) + barrier

    // ---- compute from LDS: 36 offsets + ownership totals ----
    float cc[36];
#pragma unroll
    for (int o = 0; o < 36; ++o) cc[o] = 0.f;
    float tot1 = 0.f, tot2 = 0.f;
    const bool rowOwned = (rb < NRB - 1) || (rIn < 31);  // pm rows 0..382 once

#pragma unroll
    for (int u = 0; u < 6; ++u) {
      const int row = rIn + u;
      const int r8 = row & 7;
      float pm[16];
#pragma unroll
      for (int q = 0; q < 4; ++q) {
        const int jq = 2 * s + q;
        const int js = (jq & ~7) | ((jq & 7) ^ r8);
        const int g = row * GRAN + js;
        float4 pv = *reinterpret_cast<const float4*>(&Pl[g * 4]);
        float4 mv2 = *reinterpret_cast<const float4*>(&Ml[g * 4]);
        pm[4 * q + 0] = pv.x * mv2.x;
        pm[4 * q + 1] = pv.y * mv2.y;
        pm[4 * q + 2] = pv.z * mv2.z;
        pm[4 * q + 3] = pv.w * mv2.w;
      }
      if (u == 0 && rowOwned) {   // cols rel 8s..8s+7 of owned row rIn
#pragma unroll
        for (int x = 0; x < 8; ++x) {
          tot1 += pm[x];
          tot2 = fmaf(pm[x], pm[x], tot2);
        }
      }
#pragma unroll
      for (int v = 0; v < 6; ++v) {
#pragma unroll
        for (int x = 0; x < 8; ++x) {
          cc[u * 6 + v] = fmaf(ct[x], pm[v + x], cc[u * 6 + v]);
        }
      }
    }

    // ---- block reduction: 40 floats -> mpart column-major ----
#pragma unroll
    for (int o = 0; o < 36; ++o) {
      float a = cc[o];
#pragma unroll
      for (int off = 32; off > 0; off >>= 1) a += __shfl_down(a, off);
      if (lane == 0) red[w * NM + o] = a;
    }
    {
      float a = t1, b = t2, c = tot1, d = tot2;
#pragma unroll
      for (int off = 32; off > 0; off >>= 1) {
        a += __shfl_down(a, off);
        b += __shfl_down(b, off);
        c += __shfl_down(c, off);
        d += __shfl_down(d, off);
      }
      if (lane == 0) { red[w * NM + 36] = a; red[w * NM + 37] = b; red[w * NM + 38] = c; red[w * NM + 39] = d; }
    }
    __syncthreads();
    if (t < NM) {
      mpart[t * MSTRIDE + cb] = red[0 * NM + t] + red[1 * NM + t] +
                                red[2 * NM + t] + red[3 * NM + t];
    }
  } else {
    // ---------------- edge path: blockIdx 0..63, wave-parallel ----------------
    const int img = blockIdx.x >> 1;
    const int slice = blockIdx.x & 1;
    const size_t base = (size_t)img * IMGSZ;

    if (slice == 0) {
      // full-row sums, rows {0..4, 378..382}: 4 waves, ridx = w, w+4, w+8
      for (int ridx = w; ridx < 10; ridx += 4) {
        const int row = (ridx < 5) ? ridx : (373 + ridx);
        const float* pr = predict + base + (size_t)row * 384;
        const float* mr = mask    + base + (size_t)row * 384;
        double e1 = 0.0, e2 = 0.0;
#pragma unroll
        for (int k = 0; k < 6; ++k) {
          float v = pr[lane + 64 * k] * mr[lane + 64 * k];
          e1 += v;
          e2 += (double)v * v;
        }
#pragma unroll
        for (int off = 32; off > 0; off >>= 1) {
          e1 += __shfl_down(e1, off);
          e2 += __shfl_down(e2, off);
        }
        if (lane == 0) {
          epart[(size_t)ridx        * NIMG + img] = e1;
          epart[(size_t)(10 + ridx) * NIMG + img] = e2;
        }
      }
      // corner table 10x11
      if (t < 110) {
        const int ridx = t / 11, cidx = t % 11;
        const int row = (ridx < 5) ? ridx : (373 + ridx);
        const int col = (cidx < 5) ? cidx : (373 + cidx);
        float v = predict[base + (size_t)row * 384 + col] * mask[base + (size_t)row * 384 + col];
        epart[(size_t)(42 + t)  * NIMG + img] = (double)v;
        epart[(size_t)(152 + t) * NIMG + img] = (double)v * v;
      }
    } else {
      // full-col sums, cols {0..4, 378..383}, rows 0..382
      for (int cidx = w; cidx < 11; cidx += 4) {
        const int col = (cidx < 5) ? cidx : (373 + cidx);
        double f1 = 0.0, f2 = 0.0;
#pragma unroll
        for (int k = 0; k < 6; ++k) {
          const int r = lane + 64 * k;
          if (r < 383) {
            float v = predict[base + (size_t)r * 384 + col] * mask[base + (size_t)r * 384 + col];
            f1 += v;
            f2 += (double)v * v;
          }
        }
#pragma unroll
        for (int off = 32; off > 0; off >>= 1) {
          f1 += __shfl_down(f1, off);
          f2 += __shfl_down(f2, off);
        }
        if (lane == 0) {
          epart[(size_t)(20 + cidx) * NIMG + img] = f1;
          epart[(size_t)(31 + cidx) * NIMG + img] = f2;
        }
      }
    }
  }
}

// ---------------- final kernel: assemble 36 losses, min, score ----------------
__global__ void probav_final_kernel(const float* __restrict__ mpart,
                                    const double* __restrict__ epart,
                                    float* __restrict__ out) {
  __shared__ double M[NM];
  __shared__ double E[NE];
  __shared__ double Etmp[524];
  __shared__ double loss[36];
  const int t = threadIdx.x;          // 1024 threads
  const int lane = t & 63;
  const int w = t >> 6;               // 16 waves

  for (int v = w; v < NM; v += 16) {
    const float4* qp = reinterpret_cast<const float4*>(mpart + v * MSTRIDE);
    double s = 0.0;
    for (int i = lane; i < MQUADS; i += 64) {
      float4 q = qp[i];
      s += (double)q.x + (double)q.y + (double)q.z + (double)q.w;
    }
#pragma unroll
    for (int off = 32; off > 0; off >>= 1) s += __shfl_down(s, off);
    if (lane == 0) M[v] = s;
  }
  if (t < 524) {
    const int e = t >> 1, si = t & 1;
    double s = 0.0;
    for (int i = si * 16; i < si * 16 + 16; ++i) s += epart[(size_t)e * NIMG + i];
    Etmp[t] = s;
  }
  __syncthreads();
  if (t < NE) E[t] = Etmp[2 * t] + Etmp[2 * t + 1];
  __syncthreads();

  if (t < 36) {
    const int u = t / 6, v = t % 6;
    double br1 = 0, br2 = 0, bc1 = 0, bc2 = 0, x1 = 0, x2 = 0;
    int rset[5], nr = 0;
    for (int j = 0; j < u; ++j) rset[nr++] = j;
    for (int j = 5 + u; j < 10; ++j) rset[nr++] = j;
    int cset[6], nc = 0;
    for (int j = 0; j < v; ++j) cset[nc++] = j;
    for (int j = 5 + v; j < 11; ++j) cset[nc++] = j;
    for (int a = 0; a < nr; ++a) { br1 += E[rset[a]]; br2 += E[10 + rset[a]]; }
    for (int b = 0; b < nc; ++b) { bc1 += E[20 + cset[b]]; bc2 += E[31 + cset[b]]; }
    for (int a = 0; a < nr; ++a)
      for (int b = 0; b < nc; ++b) {
        x1 += E[42 + rset[a] * 11 + cset[b]];
        x2 += E[152 + rset[a] * 11 + cset[b]];
      }
    const double T1 = M[36], T2 = M[37];
    const double W1 = M[38] - br1 - bc1 + x1;
    const double W2 = M[39] - br2 - bc2 + x2;
    const double CCv = M[t];
    const double N = 32.0 * 378.0 * 378.0;
    const double S1 = T1 - W1;
    const double S2 = T2 - 2.0 * CCv + W2;
    loss[t] = S2 / N - (S1 / N) * (S1 / N);
  }
  __syncthreads();
  if (t == 0) {
    double best = loss[0];
    for (int o = 1; o < 36; ++o) best = fmin(best, loss[o]);
    out[0] = (float)(-10.0 * log10(best));
  }
}

extern "C" void kernel_launch(void* const* d_in, const int* in_sizes, int n_in,
                              void* d_out, int out_size, void* d_ws, size_t ws_size,
                              hipStream_t stream) {
  const float* predict = (const float*)d_in[0];
  const float* target  = (const float*)d_in[1];
  const float* mask    = (const float*)d_in[2];
  float* out = (float*)d_out;

  float*  mpart = (float*)d_ws;                               // 40*2304*4 = 368640 B
  double* epart = (double*)((char*)d_ws + NM * MSTRIDE * 4);  // 262*32*8  =  67072 B

  probav_fused_kernel<<<NEDGE + NCC, 256, 0, stream>>>(predict, target, mask, mpart, epart);
  probav_final_kernel<<<1, 1024, 0, stream>>>(mpart, epart, out);
}

// Round 18
// 49.397 us; speedup vs baseline: 1.3103x; 1.3103x over previous
//
#include <hip/hip_runtime.h>
#include <hip/hip_bf16.h>
#include <math.h>

// ProbaV cPSNR:  loss(u,v) = E[d^2] - (E[d])^2,  d = ct - pm_window(u,v)
// S1(u,v) = T1 - W1(u,v);  S2(u,v) = T2 - 2*CC(u,v) + W2(u,v)
//   T1,T2   : sum ct, sum ct^2            (ct = target*mask, inner 378x378 @ +3)
//   CC(u,v) : sum ct[r][c] * pm[r+u][c+v] (pm = predict*mask)
//   W1,W2   : window sums of pm, pm^2 over rows [u,u+378) x cols [v,v+378)
// W = Total - BR(u) - BC(v) + X(u,v)  (inclusion-exclusion, rows 0..382 x cols 0..383)
//
// R18: rolling-window column walk. 17-round synthesis: perf is capped by
// per-CU cache-line-miss throughput (~8 B/cy/CU; R10 = 106MB/2.1TB/s = 50us
// exact; spill storms hit 2.4 TB/s with 4-line wave-loads). Only lever:
// total line-touches. Each thread owns 8 cols x 9 ct rows, walks 14 pm rows
// ONCE with a 6-row ct ring in registers (pm redundancy 2.67x -> 1.56x;
// 166 quads/thread per 9 rows vs R8's 246). 252 cc blocks = 1/CU, single
// generation, uniform. VGPR <256 is safe: residency target is 1 block/CU.

#define NIMG 32
#define IMGSZ (384 * 384)
#define SEGS 48                  // 8-col segments
#define NBAND 42                 // 9 ct rows per band
#define PERIMG (SEGS * NBAND)    // 2016 threads per image
#define NCC 252                  // cc blocks = 32*2016/256
#define NEDGE 64                 // 2 per image, blockIdx 0..63
#define NM 40                    // cc[36], t1, t2, tot1, tot2
#define MSTRIDE 252              // mpart col-major [NM][MSTRIDE]
#define MQUADS 63                // MSTRIDE/4
#define NE 262                   // edge entries per image

__global__ __launch_bounds__(256) void probav_fused_kernel(
    const float* __restrict__ predict,
    const float* __restrict__ target,
    const float* __restrict__ mask,
    float* __restrict__ mpart /* [NM][MSTRIDE] */,
    double* __restrict__ epart /* [NE][NIMG] */) {

  const int t = threadIdx.x;
  const int lane = t & 63;
  const int w = t >> 6;

  if (blockIdx.x >= NEDGE) {
    // ---------------- cc path: 8 cols x 9 ct rows, rolling 14 pm rows ----------------
    const int sb = blockIdx.x - NEDGE;           // 0..251
    // bijective chunked XCD swizzle on 252 = 8 XCDs (4x32 + 4x31)
    const int xc = sb & 7, idx = sb >> 3;
    const int cb = (xc < 4) ? (xc * 32 + idx) : (128 + (xc - 4) * 31 + idx);

    __shared__ float red[4 * NM];

    const int tid  = cb * 256 + t;
    const int img  = tid / PERIMG;
    const int rem  = tid - img * PERIMG;
    const int band = rem / SEGS;
    const int seg  = rem - band * SEGS;
    const int rs   = band * 9;                   // ct rows rs..rs+8 (rs <= 369)
    const int jb   = seg * 8;
    const size_t base = (size_t)img * IMGSZ;
    const int ownK = (band == NBAND - 1) ? 14 : 9;   // pm rows 0..382 owned once

    float cc[36];
#pragma unroll
    for (int o = 0; o < 36; ++o) cc[o] = 0.f;
    float ctw[6][8];
    float t1 = 0.f, t2 = 0.f, tot1 = 0.f, tot2 = 0.f;

#pragma unroll
    for (int k = 0; k < 14; ++k) {
      // ---- load ct row rs+k into ring slot k%6 (rows rs..rs+8) ----
      if (k <= 8) {
        const float* trow = target + base + (size_t)(rs + k + 3) * 384 + jb;
        const float* mrow = mask   + base + (size_t)(rs + k + 3) * 384 + jb;
        float tv[12], mv[12];
#pragma unroll
        for (int q = 0; q < 3; ++q) {
          float4 a = *reinterpret_cast<const float4*>(trow + 4 * q);
          float4 b = *reinterpret_cast<const float4*>(mrow + 4 * q);
          tv[4 * q + 0] = a.x; tv[4 * q + 1] = a.y; tv[4 * q + 2] = a.z; tv[4 * q + 3] = a.w;
          mv[4 * q + 0] = b.x; mv[4 * q + 1] = b.y; mv[4 * q + 2] = b.z; mv[4 * q + 3] = b.w;
        }
#pragma unroll
        for (int x = 0; x < 8; ++x) {
          float v = tv[3 + x] * mv[3 + x];
          v = (jb + x < 378) ? v : 0.f;
          ctw[k % 6][x] = v;
          t1 += v;
          t2 = fmaf(v, v, t2);
        }
      }

      // ---- load pm row rs+k (<= 382; 16-float window, tail garbage masked by ct=0) ----
      const float* prow = predict + base + (size_t)(rs + k) * 384 + jb;
      const float* mrw2 = mask    + base + (size_t)(rs + k) * 384 + jb;
      float pm[16];
#pragma unroll
      for (int q = 0; q < 4; ++q) {
        float4 a = *reinterpret_cast<const float4*>(prow + 4 * q);
        float4 b = *reinterpret_cast<const float4*>(mrw2 + 4 * q);
        pm[4 * q + 0] = a.x * b.x;
        pm[4 * q + 1] = a.y * b.y;
        pm[4 * q + 2] = a.z * b.z;
        pm[4 * q + 3] = a.w * b.w;
      }
      if (k < ownK) {   // ownership totals, cols jb..jb+7 (real data)
#pragma unroll
        for (int x = 0; x < 8; ++x) {
          tot1 += pm[x];
          tot2 = fmaf(pm[x], pm[x], tot2);
        }
      }

      // ---- cc: pm row rs+k pairs ct ring rows r = k-u in [0,8] ----
#pragma unroll
      for (int u = 0; u < 6; ++u) {
        const int r = k - u;
        if (r >= 0 && r <= 8) {
#pragma unroll
          for (int v = 0; v < 6; ++v) {
#pragma unroll
            for (int x = 0; x < 8; ++x) {
              cc[u * 6 + v] = fmaf(ctw[r % 6][x], pm[v + x], cc[u * 6 + v]);
            }
          }
        }
      }
    }

    // ---- block reduction: 40 floats -> mpart column-major ----
#pragma unroll
    for (int o = 0; o < 36; ++o) {
      float a = cc[o];
#pragma unroll
      for (int off = 32; off > 0; off >>= 1) a += __shfl_down(a, off);
      if (lane == 0) red[w * NM + o] = a;
    }
    {
      float a = t1, b = t2, c = tot1, d = tot2;
#pragma unroll
      for (int off = 32; off > 0; off >>= 1) {
        a += __shfl_down(a, off);
        b += __shfl_down(b, off);
        c += __shfl_down(c, off);
        d += __shfl_down(d, off);
      }
      if (lane == 0) { red[w * NM + 36] = a; red[w * NM + 37] = b; red[w * NM + 38] = c; red[w * NM + 39] = d; }
    }
    __syncthreads();
    if (t < NM) {
      mpart[t * MSTRIDE + cb] = red[0 * NM + t] + red[1 * NM + t] +
                                red[2 * NM + t] + red[3 * NM + t];
    }
  } else {
    // ---------------- edge path: blockIdx 0..63, wave-parallel, no LDS ----------------
    const int img = blockIdx.x >> 1;
    const int slice = blockIdx.x & 1;
    const size_t base = (size_t)img * IMGSZ;

    if (slice == 0) {
      // full-row sums, rows {0..4, 378..382}: 4 waves, ridx = w, w+4, w+8
      for (int ridx = w; ridx < 10; ridx += 4) {
        const int row = (ridx < 5) ? ridx : (373 + ridx);
        const float* pr = predict + base + (size_t)row * 384;
        const float* mr = mask    + base + (size_t)row * 384;
        double e1 = 0.0, e2 = 0.0;
#pragma unroll
        for (int k = 0; k < 6; ++k) {
          float v = pr[lane + 64 * k] * mr[lane + 64 * k];
          e1 += v;
          e2 += (double)v * v;
        }
#pragma unroll
        for (int off = 32; off > 0; off >>= 1) {
          e1 += __shfl_down(e1, off);
          e2 += __shfl_down(e2, off);
        }
        if (lane == 0) {
          epart[(size_t)ridx        * NIMG + img] = e1;
          epart[(size_t)(10 + ridx) * NIMG + img] = e2;
        }
      }
      // corner table 10x11
      if (t < 110) {
        const int ridx = t / 11, cidx = t % 11;
        const int row = (ridx < 5) ? ridx : (373 + ridx);
        const int col = (cidx < 5) ? cidx : (373 + cidx);
        float v = predict[base + (size_t)row * 384 + col] * mask[base + (size_t)row * 384 + col];
        epart[(size_t)(42 + t)  * NIMG + img] = (double)v;
        epart[(size_t)(152 + t) * NIMG + img] = (double)v * v;
      }
    } else {
      // full-col sums, cols {0..4, 378..383}, rows 0..382
      for (int cidx = w; cidx < 11; cidx += 4) {
        const int col = (cidx < 5) ? cidx : (373 + cidx);
        double f1 = 0.0, f2 = 0.0;
#pragma unroll
        for (int k = 0; k < 6; ++k) {
          const int r = lane + 64 * k;
          if (r < 383) {
            float v = predict[base + (size_t)r * 384 + col] * mask[base + (size_t)r * 384 + col];
            f1 += v;
            f2 += (double)v * v;
          }
        }
#pragma unroll
        for (int off = 32; off > 0; off >>= 1) {
          f1 += __shfl_down(f1, off);
          f2 += __shfl_down(f2, off);
        }
        if (lane == 0) {
          epart[(size_t)(20 + cidx) * NIMG + img] = f1;
          epart[(size_t)(31 + cidx) * NIMG + img] = f2;
        }
      }
    }
  }
}

// ---------------- final kernel: assemble 36 losses, min, score ----------------
__global__ void probav_final_kernel(const float* __restrict__ mpart,
                                    const double* __restrict__ epart,
                                    float* __restrict__ out) {
  __shared__ double M[NM];
  __shared__ double E[NE];
  __shared__ double Etmp[524];
  __shared__ double loss[36];
  const int t = threadIdx.x;          // 1024 threads
  const int lane = t & 63;
  const int w = t >> 6;               // 16 waves

  for (int v = w; v < NM; v += 16) {
    const float4* qp = reinterpret_cast<const float4*>(mpart + v * MSTRIDE);
    double s = 0.0;
    for (int i = lane; i < MQUADS; i += 64) {
      float4 q = qp[i];
      s += (double)q.x + (double)q.y + (double)q.z + (double)q.w;
    }
#pragma unroll
    for (int off = 32; off > 0; off >>= 1) s += __shfl_down(s, off);
    if (lane == 0) M[v] = s;
  }
  if (t < 524) {
    const int e = t >> 1, si = t & 1;
    double s = 0.0;
    for (int i = si * 16; i < si * 16 + 16; ++i) s += epart[(size_t)e * NIMG + i];
    Etmp[t] = s;
  }
  __syncthreads();
  if (t < NE) E[t] = Etmp[2 * t] + Etmp[2 * t + 1];
  __syncthreads();

  if (t < 36) {
    const int u = t / 6, v = t % 6;
    double br1 = 0, br2 = 0, bc1 = 0, bc2 = 0, x1 = 0, x2 = 0;
    int rset[5], nr = 0;
    for (int j = 0; j < u; ++j) rset[nr++] = j;
    for (int j = 5 + u; j < 10; ++j) rset[nr++] = j;
    int cset[6], nc = 0;
    for (int j = 0; j < v; ++j) cset[nc++] = j;
    for (int j = 5 + v; j < 11; ++j) cset[nc++] = j;
    for (int a = 0; a < nr; ++a) { br1 += E[rset[a]]; br2 += E[10 + rset[a]]; }
    for (int b = 0; b < nc; ++b) { bc1 += E[20 + cset[b]]; bc2 += E[31 + cset[b]]; }
    for (int a = 0; a < nr; ++a)
      for (int b = 0; b < nc; ++b) {
        x1 += E[42 + rset[a] * 11 + cset[b]];
        x2 += E[152 + rset[a] * 11 + cset[b]];
      }
    const double T1 = M[36], T2 = M[37];
    const double W1 = M[38] - br1 - bc1 + x1;
    const double W2 = M[39] - br2 - bc2 + x2;
    const double CCv = M[t];
    const double N = 32.0 * 378.0 * 378.0;
    const double S1 = T1 - W1;
    const double S2 = T2 - 2.0 * CCv + W2;
    loss[t] = S2 / N - (S1 / N) * (S1 / N);
  }
  __syncthreads();
  if (t == 0) {
    double best = loss[0];
    for (int o = 1; o < 36; ++o) best = fmin(best, loss[o]);
    out[0] = (float)(-10.0 * log10(best));
  }
}

extern "C" void kernel_launch(void* const* d_in, const int* in_sizes, int n_in,
                              void* d_out, int out_size, void* d_ws, size_t ws_size,
                              hipStream_t stream) {
  const float* predict = (const float*)d_in[0];
  const float* target  = (const float*)d_in[1];
  const float* mask    = (const float*)d_in[2];
  float* out = (float*)d_out;

  float*  mpart = (float*)d_ws;                               // 40*252*4 = 40320 B
  double* epart = (double*)((char*)d_ws + NM * MSTRIDE * 4);  // 262*32*8 = 67072 B

  probav_fused_kernel<<<NEDGE + NCC, 256, 0, stream>>>(predict, target, mask, mpart, epart);
  probav_final_kernel<<<1, 1024, 0, stream>>>(mpart, epart, out);
}